// Round 3
// baseline (282.239 us; speedup 1.0000x reference)
//
#include <hip/hip_runtime.h>

#define SEQ 4096
#define EMB 1024
#define HS 64

typedef __attribute__((ext_vector_type(8))) short bf16x8;
typedef __attribute__((ext_vector_type(4))) float f32x4;

__device__ __forceinline__ unsigned short f2b(float f) {
    union { float f; unsigned u; } v; v.f = f;
    unsigned r = v.u + 0x7fffu + ((v.u >> 16) & 1u);
    return (unsigned short)(r >> 16);
}

// ---------- W transpose + cast: Wt[192][1024] bf16; rows 0-63=Q (pre-scaled), 64-127=K, 128-191=V
__global__ __launch_bounds__(256) void wt_kernel(const float* __restrict__ Wq,
                                                 const float* __restrict__ Wk,
                                                 const float* __restrict__ Wv,
                                                 unsigned short* __restrict__ Wt) {
    int id = blockIdx.x * 256 + threadIdx.x;   // [0, 3*1024*64)
    int mat = id >> 16;
    int rem = id & 65535;
    int k = rem >> 6;
    int n = rem & 63;
    const float* W = (mat == 0) ? Wq : (mat == 1) ? Wk : Wv;
    // fold softmax scale (1/8) * log2(e) into Q projection (absorbed pre-quantization)
    float scale = (mat == 0) ? 0.125f * 1.44269504f : 1.0f;
    Wt[(mat * HS + n) * EMB + k] = f2b(W[k * HS + n] * scale);
}

// ---------- fused QKV projection, barrier-free, one wave per 16 rows ----------
// Qb[16384][64], Kb[16384][64] bf16 row-major; Vt[4][64][4096] bf16 (h-major, pre-transposed)
__global__ __launch_bounds__(64) void proj_kernel(const float* __restrict__ x,
                                                  const unsigned short* __restrict__ Wt,
                                                  unsigned short* __restrict__ Qb,
                                                  unsigned short* __restrict__ Kb,
                                                  unsigned short* __restrict__ Vt) {
    const int lane = threadIdx.x;
    const int col = lane & 15, quad = lane >> 4;
    const int m0 = blockIdx.x * 16;
    const int b = m0 >> 12, t0 = m0 & 4095;

    f32x4 acc[12];
    #pragma unroll
    for (int i = 0; i < 12; i++) acc[i] = (f32x4){0.f, 0.f, 0.f, 0.f};

    for (int k0 = 0; k0 < EMB; k0 += 64) {
        bf16x8 af[2];
        #pragma unroll
        for (int c = 0; c < 2; c++) {
            const float* xp = x + (size_t)(m0 + col) * EMB + k0 + quad * 8 + c * 32;
            float4 lo = *(const float4*)xp;
            float4 hi = *(const float4*)(xp + 4);
            bf16x8 a;
            a[0] = (short)f2b(lo.x); a[1] = (short)f2b(lo.y);
            a[2] = (short)f2b(lo.z); a[3] = (short)f2b(lo.w);
            a[4] = (short)f2b(hi.x); a[5] = (short)f2b(hi.y);
            a[6] = (short)f2b(hi.z); a[7] = (short)f2b(hi.w);
            af[c] = a;
        }
        #pragma unroll
        for (int nt = 0; nt < 12; nt++)
            #pragma unroll
            for (int c = 0; c < 2; c++) {
                bf16x8 bf = *(const bf16x8*)(Wt + (size_t)(nt * 16 + col) * EMB + k0 + quad * 8 + c * 32);
                acc[nt] = __builtin_amdgcn_mfma_f32_16x16x32_bf16(af[c], bf, acc[nt], 0, 0, 0);
            }
    }
    // epilogue: C/D layout row=quad*4+r, col=lane&15
    #pragma unroll
    for (int nt = 0; nt < 4; nt++)
        #pragma unroll
        for (int r = 0; r < 4; r++)
            Qb[(size_t)(m0 + quad * 4 + r) * HS + nt * 16 + col] = f2b(acc[nt][r]);
    #pragma unroll
    for (int nt = 0; nt < 4; nt++)
        #pragma unroll
        for (int r = 0; r < 4; r++)
            Kb[(size_t)(m0 + quad * 4 + r) * HS + nt * 16 + col] = f2b(acc[4 + nt][r]);
    #pragma unroll
    for (int nt = 0; nt < 4; nt++) {
        int h = nt * 16 + col;
        #pragma unroll
        for (int r = 0; r < 4; r++)
            Vt[((size_t)b * HS + h) * SEQ + t0 + quad * 4 + r] = f2b(acc[8 + nt][r]);
    }
}

// ---------- flash attention (causal), barrier-free, one wave per 16 Q rows ----------
__global__ __launch_bounds__(64) void attn_kernel(const unsigned short* __restrict__ Qb,
                                                  const unsigned short* __restrict__ Kb,
                                                  const unsigned short* __restrict__ Vt,
                                                  float* __restrict__ out) {
    __shared__ unsigned short P_lds[16 * 72];
    const int lane = threadIdx.x;
    const int col = lane & 15, quad = lane >> 4;
    const int tile = 255 - (blockIdx.x >> 2);   // longest-first launch order
    const int b = blockIdx.x & 3;
    const int q0 = tile * 16;
    const size_t qrow = (size_t)(b << 12) + q0;

    bf16x8 qf[2];
    #pragma unroll
    for (int c = 0; c < 2; c++)
        qf[c] = *(const bf16x8*)(Qb + (qrow + col) * HS + quad * 8 + c * 32);

    f32x4 o[4];
    float l[4];
    #pragma unroll
    for (int ct = 0; ct < 4; ct++) o[ct] = (f32x4){0.f, 0.f, 0.f, 0.f};
    #pragma unroll
    for (int r = 0; r < 4; r++) l[r] = 0.f;

    const int ns = (q0 + 16 + 63) >> 6;
    const size_t krow0 = (size_t)(b << 12);
    const size_t vrow0 = (size_t)b * HS;

    for (int s = 0; s < ns; s++) {
        const int kv0 = s << 6;
        // S = Q K^T, 16x64, Q pre-scaled by 0.125*log2e
        f32x4 sacc[4];
        #pragma unroll
        for (int ct = 0; ct < 4; ct++) sacc[ct] = (f32x4){0.f, 0.f, 0.f, 0.f};
        #pragma unroll
        for (int ct = 0; ct < 4; ct++)
            #pragma unroll
            for (int c = 0; c < 2; c++) {
                bf16x8 kf = *(const bf16x8*)(Kb + (krow0 + kv0 + ct * 16 + col) * HS + quad * 8 + c * 32);
                sacc[ct] = __builtin_amdgcn_mfma_f32_16x16x32_bf16(qf[c], kf, sacc[ct], 0, 0, 0);
            }

        // max-free softmax accumulation: p = 2^s (s already includes 1/8*log2e)
        const bool lastT = (s == ns - 1);
        float p[4][4], rsum[4];
        #pragma unroll
        for (int r = 0; r < 4; r++) rsum[r] = 0.f;
        #pragma unroll
        for (int ct = 0; ct < 4; ct++) {
            int cg = kv0 + ct * 16 + col;
            #pragma unroll
            for (int r = 0; r < 4; r++) {
                int rg = q0 + quad * 4 + r;
                float e = __builtin_exp2f(sacc[ct][r]);
                p[ct][r] = (lastT && cg > rg) ? 0.f : e;
                rsum[r] += p[ct][r];
            }
        }
        #pragma unroll
        for (int off = 1; off < 16; off <<= 1)
            #pragma unroll
            for (int r = 0; r < 4; r++)
                rsum[r] += __shfl_xor(rsum[r], off, 64);
        #pragma unroll
        for (int r = 0; r < 4; r++) l[r] += rsum[r];

        // P: C-layout -> (wave-private LDS) -> A-layout
        #pragma unroll
        for (int ct = 0; ct < 4; ct++)
            #pragma unroll
            for (int r = 0; r < 4; r++)
                P_lds[(quad * 4 + r) * 72 + ct * 16 + col] = f2b(p[ct][r]);
        bf16x8 pf[2];
        #pragma unroll
        for (int c = 0; c < 2; c++)
            pf[c] = *(const bf16x8*)&P_lds[col * 72 + quad * 8 + c * 32];

        // O += P V, V^T fragments direct from Vt
        #pragma unroll
        for (int ct = 0; ct < 4; ct++)
            #pragma unroll
            for (int c = 0; c < 2; c++) {
                bf16x8 vf = *(const bf16x8*)(Vt + (vrow0 + ct * 16 + col) * SEQ + kv0 + quad * 8 + c * 32);
                o[ct] = __builtin_amdgcn_mfma_f32_16x16x32_bf16(pf[c], vf, o[ct], 0, 0, 0);
            }
    }

    #pragma unroll
    for (int ct = 0; ct < 4; ct++)
        #pragma unroll
        for (int r = 0; r < 4; r++)
            out[(qrow + quad * 4 + r) * HS + ct * 16 + col] = o[ct][r] / l[r];
}

extern "C" void kernel_launch(void* const* d_in, const int* in_sizes, int n_in,
                              void* d_out, int out_size, void* d_ws, size_t ws_size,
                              hipStream_t stream) {
    const float* x  = (const float*)d_in[0];
    const float* Wk = (const float*)d_in[1];
    const float* Wq = (const float*)d_in[2];
    const float* Wv = (const float*)d_in[3];
    float* out = (float*)d_out;

    unsigned short* Wt = (unsigned short*)d_ws;                        // 192*1024*2   = 393216 B
    unsigned short* Qb = (unsigned short*)((char*)d_ws + 393216);      // 16384*64*2   = 2 MiB
    unsigned short* Kb = (unsigned short*)((char*)d_ws + 393216 + (1u<<21));
    unsigned short* Vt = (unsigned short*)((char*)d_ws + 393216 + (2u<<21));

    wt_kernel<<<dim3(768), dim3(256), 0, stream>>>(Wq, Wk, Wv, Wt);
    proj_kernel<<<dim3(1024), dim3(64), 0, stream>>>(x, Wt, Qb, Kb, Vt);
    attn_kernel<<<dim3(1024), dim3(64), 0, stream>>>(Qb, Kb, Vt, out);
}

// Round 4
// 234.528 us; speedup vs baseline: 1.2034x; 1.2034x over previous
//
#include <hip/hip_runtime.h>

#define SEQ 4096
#define EMB 1024
#define HS 64

typedef __attribute__((ext_vector_type(8))) short bf16x8;
typedef __attribute__((ext_vector_type(4))) float f32x4;

__device__ __forceinline__ unsigned short f2b(float f) {
    union { float f; unsigned u; } v; v.f = f;
    unsigned r = v.u + 0x7fffu + ((v.u >> 16) & 1u);
    return (unsigned short)(r >> 16);
}

// ---------- W transpose + cast: Wt[192][1024] bf16; rows 0-63=Q (pre-scaled), 64-127=K, 128-191=V
__global__ __launch_bounds__(256) void wt_kernel(const float* __restrict__ Wq,
                                                 const float* __restrict__ Wk,
                                                 const float* __restrict__ Wv,
                                                 unsigned short* __restrict__ Wt) {
    int id = blockIdx.x * 256 + threadIdx.x;
    int mat = id >> 16;
    int rem = id & 65535;
    int k = rem >> 6;
    int n = rem & 63;
    const float* W = (mat == 0) ? Wq : (mat == 1) ? Wk : Wv;
    float scale = (mat == 0) ? 0.125f * 1.44269504f : 1.0f;   // fold 1/sqrt(64) * log2(e) into Q
    Wt[(mat * HS + n) * EMB + k] = f2b(W[k * HS + n] * scale);
}

// ---------- fused QKV projection, one wave per 16 rows, batched loads + x prefetch ----------
__global__ __launch_bounds__(64, 2) void proj_kernel(const float* __restrict__ x,
                                                     const unsigned short* __restrict__ Wt,
                                                     unsigned short* __restrict__ Qb,
                                                     unsigned short* __restrict__ Kb,
                                                     unsigned short* __restrict__ Vt) {
    const int lane = threadIdx.x;
    const int col = lane & 15, quad = lane >> 4;
    const int m0 = blockIdx.x * 16;
    const int b = m0 >> 12, t0 = m0 & 4095;

    f32x4 acc[12];
    #pragma unroll
    for (int i = 0; i < 12; i++) acc[i] = (f32x4){0.f, 0.f, 0.f, 0.f};

    const float* xp = x + (size_t)(m0 + col) * EMB + quad * 8;

    float4 nxt0 = *(const float4*)(xp + 0);
    float4 nxt1 = *(const float4*)(xp + 4);
    float4 nxt2 = *(const float4*)(xp + 32);
    float4 nxt3 = *(const float4*)(xp + 36);

    for (int k0 = 0; k0 < EMB; k0 += 64) {
        float4 c0 = nxt0, c1 = nxt1, c2 = nxt2, c3 = nxt3;
        if (k0 + 64 < EMB) {
            nxt0 = *(const float4*)(xp + k0 + 64);
            nxt1 = *(const float4*)(xp + k0 + 68);
            nxt2 = *(const float4*)(xp + k0 + 96);
            nxt3 = *(const float4*)(xp + k0 + 100);
        }
        // batch all 24 Wt fragment loads
        bf16x8 bfr[12][2];
        #pragma unroll
        for (int nt = 0; nt < 12; nt++) {
            const unsigned short* wp = Wt + (size_t)(nt * 16 + col) * EMB + k0 + quad * 8;
            bfr[nt][0] = *(const bf16x8*)(wp);
            bfr[nt][1] = *(const bf16x8*)(wp + 32);
        }
        bf16x8 af[2];
        af[0][0] = (short)f2b(c0.x); af[0][1] = (short)f2b(c0.y);
        af[0][2] = (short)f2b(c0.z); af[0][3] = (short)f2b(c0.w);
        af[0][4] = (short)f2b(c1.x); af[0][5] = (short)f2b(c1.y);
        af[0][6] = (short)f2b(c1.z); af[0][7] = (short)f2b(c1.w);
        af[1][0] = (short)f2b(c2.x); af[1][1] = (short)f2b(c2.y);
        af[1][2] = (short)f2b(c2.z); af[1][3] = (short)f2b(c2.w);
        af[1][4] = (short)f2b(c3.x); af[1][5] = (short)f2b(c3.y);
        af[1][6] = (short)f2b(c3.z); af[1][7] = (short)f2b(c3.w);
        #pragma unroll
        for (int nt = 0; nt < 12; nt++)
            #pragma unroll
            for (int c = 0; c < 2; c++)
                acc[nt] = __builtin_amdgcn_mfma_f32_16x16x32_bf16(af[c], bfr[nt][c], acc[nt], 0, 0, 0);
    }
    #pragma unroll
    for (int nt = 0; nt < 4; nt++)
        #pragma unroll
        for (int r = 0; r < 4; r++)
            Qb[(size_t)(m0 + quad * 4 + r) * HS + nt * 16 + col] = f2b(acc[nt][r]);
    #pragma unroll
    for (int nt = 0; nt < 4; nt++)
        #pragma unroll
        for (int r = 0; r < 4; r++)
            Kb[(size_t)(m0 + quad * 4 + r) * HS + nt * 16 + col] = f2b(acc[4 + nt][r]);
    #pragma unroll
    for (int nt = 0; nt < 4; nt++) {
        int h = nt * 16 + col;
        #pragma unroll
        for (int r = 0; r < 4; r++)
            Vt[((size_t)b * HS + h) * SEQ + t0 + quad * 4 + r] = f2b(acc[8 + nt][r]);
    }
}

// ---------- flash attention (causal), split-KV x4, one wave per (tile, split) ----------
__global__ __launch_bounds__(64, 3) void attn_kernel(const unsigned short* __restrict__ Qb,
                                                     const unsigned short* __restrict__ Kb,
                                                     const unsigned short* __restrict__ Vt,
                                                     float* __restrict__ Opart,
                                                     float* __restrict__ Lpart) {
    __shared__ unsigned short P_lds[16 * 72];
    const int lane = threadIdx.x;
    const int col = lane & 15, quad = lane >> 4;
    const int bid = blockIdx.x;            // 4096
    const int split = bid & 3;
    const int b = (bid >> 2) & 3;
    const int tile = 255 - (bid >> 4);     // longest-first
    const int q0 = tile * 16;
    const size_t qrow = (size_t)(b << 12) + q0;

    const int ns = (q0 + 79) >> 6;         // KV blocks covering [0, q0+16)
    const int s_beg = (ns * split) >> 2;
    const int s_end = (ns * (split + 1)) >> 2;

    bf16x8 qf[2];
    #pragma unroll
    for (int c = 0; c < 2; c++)
        qf[c] = *(const bf16x8*)(Qb + (qrow + col) * HS + quad * 8 + c * 32);

    f32x4 o[4];
    float l[4];
    #pragma unroll
    for (int ct = 0; ct < 4; ct++) o[ct] = (f32x4){0.f, 0.f, 0.f, 0.f};
    #pragma unroll
    for (int r = 0; r < 4; r++) l[r] = 0.f;

    const unsigned short* Kp = Kb + ((size_t)(b << 12)) * HS;
    const unsigned short* Vp = Vt + (size_t)b * HS * SEQ;

    for (int s = s_beg; s < s_end; s++) {
        const int kv0 = s << 6;
        // batch all 8 K fragment loads
        bf16x8 kf[4][2];
        #pragma unroll
        for (int ct = 0; ct < 4; ct++) {
            const unsigned short* kp = Kp + (size_t)(kv0 + ct * 16 + col) * HS + quad * 8;
            kf[ct][0] = *(const bf16x8*)(kp);
            kf[ct][1] = *(const bf16x8*)(kp + 32);
        }
        f32x4 sacc[4];
        #pragma unroll
        for (int ct = 0; ct < 4; ct++) sacc[ct] = (f32x4){0.f, 0.f, 0.f, 0.f};
        #pragma unroll
        for (int ct = 0; ct < 4; ct++)
            #pragma unroll
            for (int c = 0; c < 2; c++)
                sacc[ct] = __builtin_amdgcn_mfma_f32_16x16x32_bf16(qf[c], kf[ct][c], sacc[ct], 0, 0, 0);

        // issue V loads early; latency overlaps softmax VALU
        bf16x8 vf[4][2];
        #pragma unroll
        for (int ct = 0; ct < 4; ct++) {
            const unsigned short* vp = Vp + (size_t)(ct * 16 + col) * SEQ + kv0 + quad * 8;
            vf[ct][0] = *(const bf16x8*)(vp);
            vf[ct][1] = *(const bf16x8*)(vp + 32);
        }

        // max-free softmax: p = 2^s (scale folded into Q)
        const bool lastT = (s == ns - 1);
        float p[4][4], rsum[4];
        #pragma unroll
        for (int r = 0; r < 4; r++) rsum[r] = 0.f;
        #pragma unroll
        for (int ct = 0; ct < 4; ct++) {
            int cg = kv0 + ct * 16 + col;
            #pragma unroll
            for (int r = 0; r < 4; r++) {
                int rg = q0 + quad * 4 + r;
                float e = __builtin_exp2f(sacc[ct][r]);
                p[ct][r] = (lastT && cg > rg) ? 0.f : e;
                rsum[r] += p[ct][r];
            }
        }
        #pragma unroll
        for (int off = 1; off < 16; off <<= 1)
            #pragma unroll
            for (int r = 0; r < 4; r++)
                rsum[r] += __shfl_xor(rsum[r], off, 64);
        #pragma unroll
        for (int r = 0; r < 4; r++) l[r] += rsum[r];

        // P: C-layout -> wave-private LDS -> A-layout
        #pragma unroll
        for (int ct = 0; ct < 4; ct++)
            #pragma unroll
            for (int r = 0; r < 4; r++)
                P_lds[(quad * 4 + r) * 72 + ct * 16 + col] = f2b(p[ct][r]);
        bf16x8 pf[2];
        #pragma unroll
        for (int c = 0; c < 2; c++)
            pf[c] = *(const bf16x8*)&P_lds[col * 72 + quad * 8 + c * 32];

        #pragma unroll
        for (int ct = 0; ct < 4; ct++)
            #pragma unroll
            for (int c = 0; c < 2; c++)
                o[ct] = __builtin_amdgcn_mfma_f32_16x16x32_bf16(pf[c], vf[ct][c], o[ct], 0, 0, 0);
    }

    // write partials (always, even if split empty -> zeros)
    const int idx = (((b << 8) + tile) << 2) + split;
    float* Op = Opart + (size_t)idx * 1024;
    #pragma unroll
    for (int ct = 0; ct < 4; ct++)
        #pragma unroll
        for (int r = 0; r < 4; r++)
            Op[(quad * 4 + r) * 64 + ct * 16 + col] = o[ct][r];
    if (col == 0) {
        #pragma unroll
        for (int r = 0; r < 4; r++)
            Lpart[idx * 16 + quad * 4 + r] = l[r];
    }
}

// ---------- combine split-KV partials ----------
__global__ __launch_bounds__(256) void comb_kernel(const float* __restrict__ Opart,
                                                   const float* __restrict__ Lpart,
                                                   float* __restrict__ out) {
    int gid = blockIdx.x * 256 + threadIdx.x;   // 262144
    int row = gid >> 4;                          // 0..16383
    int c4 = (gid & 15) * 4;
    int t = row & 4095;
    int tile = t >> 4, rin = t & 15;
    int tIdx = ((row >> 12) << 8) + tile;

    float4 acc = make_float4(0.f, 0.f, 0.f, 0.f);
    float l = 0.f;
    #pragma unroll
    for (int s = 0; s < 4; s++) {
        int idx = (tIdx << 2) + s;
        float4 v = *(const float4*)(Opart + (size_t)idx * 1024 + rin * 64 + c4);
        acc.x += v.x; acc.y += v.y; acc.z += v.z; acc.w += v.w;
        l += Lpart[idx * 16 + rin];
    }
    float inv = 1.f / l;
    float4 res = make_float4(acc.x * inv, acc.y * inv, acc.z * inv, acc.w * inv);
    *(float4*)(out + (size_t)row * HS + c4) = res;
}

extern "C" void kernel_launch(void* const* d_in, const int* in_sizes, int n_in,
                              void* d_out, int out_size, void* d_ws, size_t ws_size,
                              hipStream_t stream) {
    const float* x  = (const float*)d_in[0];
    const float* Wk = (const float*)d_in[1];
    const float* Wq = (const float*)d_in[2];
    const float* Wv = (const float*)d_in[3];
    float* out = (float*)d_out;

    char* ws = (char*)d_ws;
    unsigned short* Wt = (unsigned short*)(ws);                 // 393216 B
    unsigned short* Qb = (unsigned short*)(ws + 393216);        // 2 MiB
    unsigned short* Kb = (unsigned short*)(ws + 2490368);       // 2 MiB
    unsigned short* Vt = (unsigned short*)(ws + 4587520);       // 2 MiB
    float* Opart       = (float*)(ws + 6684672);                // 16.78 MB
    float* Lpart       = (float*)(ws + 23461888);               // 256 KB

    wt_kernel<<<dim3(768), dim3(256), 0, stream>>>(Wq, Wk, Wv, Wt);
    proj_kernel<<<dim3(1024), dim3(64), 0, stream>>>(x, Wt, Qb, Kb, Vt);
    attn_kernel<<<dim3(4096), dim3(64), 0, stream>>>(Qb, Kb, Vt, Opart, Lpart);
    comb_kernel<<<dim3(1024), dim3(256), 0, stream>>>(Opart, Lpart, out);
}